// Round 1
// baseline (36.867 us; speedup 1.0000x reference)
//
#include <hip/hip_runtime.h>
#include <math.h>

#define EDGE_DIM 3
#define NUM_HEADS 8
#define HIDDEN 16

// Per-edge tiny MLP: (3) -> (16) relu -> (8)
__device__ __forceinline__ void edge_mlp(const float a0, const float a1, const float a2,
                                         const float* __restrict__ W1,
                                         const float* __restrict__ b1,
                                         const float* __restrict__ W2,
                                         const float* __restrict__ b2,
                                         float* o /* [NUM_HEADS] */) {
    float h[HIDDEN];
#pragma unroll
    for (int j = 0; j < HIDDEN; ++j) {
        float s = b1[j];
        s += a0 * W1[0 * HIDDEN + j];
        s += a1 * W1[1 * HIDDEN + j];
        s += a2 * W1[2 * HIDDEN + j];
        h[j] = s > 0.0f ? s : 0.0f;
    }
#pragma unroll
    for (int i = 0; i < NUM_HEADS; ++i) {
        float s = b2[i];
#pragma unroll
        for (int j = 0; j < HIDDEN; ++j) s += h[j] * W2[j * NUM_HEADS + i];
        o[i] = s;
    }
}

// Pass 2: deterministic winner per (src,dst) slot = max edge index.
// Marker (e+1) stored as uint in word 0 of the slot (buffer was zeroed).
__global__ void k_mark(const int* __restrict__ ei, float* __restrict__ out,
                       int E, int N) {
    int e = blockIdx.x * blockDim.x + threadIdx.x;
    if (e >= E) return;
    int src = ei[e];
    int dst = ei[E + e];
    size_t slot = (size_t)src * (size_t)N + (size_t)dst;
    unsigned* p = (unsigned*)(out + slot * NUM_HEADS);
    atomicMax(p, (unsigned)(e + 1));
}

// Pass 3: winners write words 1..7 (word 0 = marker stays intact; race-free).
__global__ void k_write17(const int* __restrict__ ei, const float* __restrict__ ea,
                          const float* __restrict__ W1, const float* __restrict__ b1,
                          const float* __restrict__ W2, const float* __restrict__ b2,
                          float* __restrict__ out, int E, int N) {
    int e = blockIdx.x * blockDim.x + threadIdx.x;
    if (e >= E) return;
    int src = ei[e];
    int dst = ei[E + e];
    size_t slot = (size_t)src * (size_t)N + (size_t)dst;
    float* p = out + slot * NUM_HEADS;
    unsigned m = *(const unsigned*)p;
    if (m != (unsigned)(e + 1)) return;  // not the winner
    float o[NUM_HEADS];
    edge_mlp(ea[e * EDGE_DIM + 0], ea[e * EDGE_DIM + 1], ea[e * EDGE_DIM + 2],
             W1, b1, W2, b2, o);
#pragma unroll
    for (int i = 1; i < NUM_HEADS; ++i) p[i] = o[i];
}

// Pass 4: winners overwrite word 0 with the float value. A losing duplicate
// reading word 0 concurrently could only false-positive if the float's bit
// pattern equals its own (f+1) <= E, i.e. a denormal < 1e-40 — we flush those
// to 0.0f so the comparison is provably hazard-free and deterministic.
__global__ void k_write0(const int* __restrict__ ei, const float* __restrict__ ea,
                         const float* __restrict__ W1, const float* __restrict__ b1,
                         const float* __restrict__ W2, const float* __restrict__ b2,
                         float* __restrict__ out, int E, int N) {
    int e = blockIdx.x * blockDim.x + threadIdx.x;
    if (e >= E) return;
    int src = ei[e];
    int dst = ei[E + e];
    size_t slot = (size_t)src * (size_t)N + (size_t)dst;
    float* p = out + slot * NUM_HEADS;
    unsigned m = *(const unsigned*)p;
    if (m != (unsigned)(e + 1)) return;  // not the winner
    float o[NUM_HEADS];
    edge_mlp(ea[e * EDGE_DIM + 0], ea[e * EDGE_DIM + 1], ea[e * EDGE_DIM + 2],
             W1, b1, W2, b2, o);
    float v = o[0];
    unsigned u = __float_as_uint(v);
    if (u >= 1u && u <= (unsigned)E) v = 0.0f;  // flush marker-aliasing denormals
    p[0] = v;
}

extern "C" void kernel_launch(void* const* d_in, const int* in_sizes, int n_in,
                              void* d_out, int out_size, void* d_ws, size_t ws_size,
                              hipStream_t stream) {
    const int* ei   = (const int*)d_in[0];    // (2, E) int32
    const float* ea = (const float*)d_in[1];  // (E, 3) f32
    // d_in[2] = num_nodes scalar (device); derive N from out_size instead.
    const float* W1 = (const float*)d_in[3];  // (3, 16)
    const float* b1 = (const float*)d_in[4];  // (16,)
    const float* W2 = (const float*)d_in[5];  // (16, 8)
    const float* b2 = (const float*)d_in[6];  // (8,)
    float* out = (float*)d_out;

    const int E = in_sizes[0] / 2;
    const int N = (int)(sqrt((double)(out_size / NUM_HEADS)) + 0.5);

    // Pass 1: zero the dense output (the 134 MB roofline term).
    hipMemsetAsync(d_out, 0, (size_t)out_size * sizeof(float), stream);

    const int blk = 256;
    const int grid = (E + blk - 1) / blk;
    k_mark<<<grid, blk, 0, stream>>>(ei, out, E, N);
    k_write17<<<grid, blk, 0, stream>>>(ei, ea, W1, b1, W2, b2, out, E, N);
    k_write0<<<grid, blk, 0, stream>>>(ei, ea, W1, b1, W2, b2, out, E, N);
}